// Round 2
// baseline (8325.661 us; speedup 1.0000x reference)
//
#include <hip/hip_runtime.h>
#include <math.h>

#define B_   2048
#define T_   100
#define V_   20000
#define VP   20480
#define KP   128
#define TP   112
#define NC2  32
#define CH2  640
#define LDV  72    // vv LDS row stride (shorts): 144B = 16B-aligned, 2-way banks (free)

typedef short s8v __attribute__((ext_vector_type(8)));
typedef short s4v __attribute__((ext_vector_type(4)));
typedef float f4  __attribute__((ext_vector_type(4)));

__device__ __forceinline__ short f2bf(float f) {
    unsigned u = __builtin_bit_cast(unsigned, f);
    u += 0x7fffu + ((u >> 16) & 1u);
    return (short)(u >> 16);
}
__device__ __forceinline__ float bf2f(short h) {
    unsigned u = ((unsigned)(unsigned short)h) << 16;
    return __builtin_bit_cast(float, u);
}
#define MFMA(a,b,c) __builtin_amdgcn_mfma_f32_16x16x32_bf16((a),(b),(c),0,0,0)

// A1[v][t] = exp(-lam*M[t][v]) bf16 (t-pad to 128, v-pad to VP, zeros)
// W1[v][t] = 1 - M[t][v] bf16 (same pads)
__global__ void k_initKT(const float* __restrict__ M, const int* __restrict__ alpha,
                         short* __restrict__ A1, short* __restrict__ W1) {
    __shared__ float tile[32][33];
    float lam = (float)(*alpha);
    int v0 = blockIdx.x * 32, t0 = blockIdx.y * 32;
    int tx = threadIdx.x, ty = threadIdx.y;
    for (int j = 0; j < 4; ++j) {
        int t = t0 + ty + 8 * j, v = v0 + tx;
        tile[ty + 8 * j][tx] = (t < T_ && v < V_) ? M[(size_t)t * V_ + v] : 0.f;
    }
    __syncthreads();
    for (int j = 0; j < 4; ++j) {
        int t = t0 + tx, v = v0 + ty + 8 * j;
        float m = tile[tx][ty + 8 * j];
        bool valid = (t < T_) && (v < V_);
        A1[(size_t)v * KP + t] = valid ? f2bf(__expf(-m * lam)) : (short)0;
        W1[(size_t)v * KP + t] = valid ? f2bf(1.f - m) : (short)0;
    }
}

// A2[t][v] = K bf16, A2M[t][v] = K*M bf16; [TP][VP] zero-padded
__global__ void k_initA2(const float* __restrict__ M, const int* __restrict__ alpha,
                         short* __restrict__ A2, short* __restrict__ A2M) {
    float lam = (float)(*alpha);
    size_t id = (size_t)blockIdx.x * 256 + threadIdx.x;   // < TP*VP
    int t = (int)(id / VP), v = (int)(id % VP);
    bool valid = (t < T_) && (v < V_);
    float m = valid ? M[(size_t)t * V_ + v] : 0.f;
    float k = valid ? __expf(-m * lam) : 0.f;
    A2[id]  = valid ? f2bf(k) : (short)0;
    A2M[id] = valid ? f2bf(k * m) : (short)0;
}

// uT init (1/T in bf16, pads zero) + zero rec accumulators
__global__ void k_init0(short* __restrict__ uTbf, float* __restrict__ recSE,
                        float* __restrict__ recSXL, float* __restrict__ recSX) {
    int id = blockIdx.x * 256 + threadIdx.x;   // < B_*KP
    int t = id & (KP - 1);
    uTbf[id] = (t < T_) ? f2bf(0.01f) : (short)0;
    if (id < B_) { recSE[id] = 0.f; recSXL[id] = 0.f; recSX[id] = 0.f; }
}

// dwbf[b][v] = bf16(dw[b][v]) flat
__global__ void k_castdw(const float* __restrict__ dw, short* __restrict__ dwbf) {
    size_t base = ((size_t)blockIdx.x * 256 + threadIdx.x) * 8;   // < B_*V_
    f4 x0 = *(const f4*)(dw + base);
    f4 x1 = *(const f4*)(dw + base + 4);
    s8v o;
    o[0]=f2bf(x0[0]); o[1]=f2bf(x0[1]); o[2]=f2bf(x0[2]); o[3]=f2bf(x0[3]);
    o[4]=f2bf(x1[0]); o[5]=f2bf(x1[1]); o[6]=f2bf(x1[2]); o[7]=f2bf(x1[3]);
    *(s8v*)(dwbf + base) = o;
}

// dtbf[b][t] bf16, t-pad 128
__global__ void k_castdt(const float* __restrict__ dt, short* __restrict__ dtbf) {
    int id = blockIdx.x * 256 + threadIdx.x;   // < B_*KP
    int b = id >> 7, t = id & (KP - 1);
    dtbf[id] = (t < T_) ? f2bf(dt[(size_t)b * T_ + t]) : (short)0;
}

// Fused Sinkhorn iteration kernel (64 b-rows/block, 1024 blocks = 4 blocks/CU):
//   per v-strip (64): den [v][b] = A1-frag @ uT-frag (MFMA, D row=v col=b)
//                     -> each lane holds 4 consecutive v at fixed b:
//                        dw read = one s4v load; vv -> LDS = one b64 write
//                     C2[t][b] += A2acc[:,strip] @ vv^T (B-frags from LDS [b][v])
//   part2[c][b][t] written once at the end (split-K over 32 chunks).
//   blockIdx swizzled so each XCD (id%8) owns 4 consecutive v-chunks (A-slices
//   ~1.2MB fit the 4MB per-XCD L2).
__global__ __launch_bounds__(256, 4) void k_GF(const short* __restrict__ A1,
                                               const short* __restrict__ A2acc,
                                               const short* __restrict__ uT,
                                               const short* __restrict__ dwbf,
                                               float* __restrict__ part2) {
    __shared__ short vv[2][64 * LDV];
    int tid = threadIdx.x;
    int wave = tid >> 6, lane = tid & 63, q = lane >> 4, l16 = lane & 15;

    // bijective swizzle: linear id l -> (bx, c) with XCD (l%8) -> chunks 4x..4x+3
    int l = blockIdx.x;
    int j = l & 31, bx = l >> 5;
    int c = ((j & 7) << 2) | (j >> 3);
    int v0 = c * CH2;
    int b0 = bx * 64;
    int bw = b0 + wave * 16;
    int bg = bw + l16;                 // this thread's b (uT col, dw row, part2 col)
    const size_t dwrow = (size_t)bg * V_;

    // hoisted uT B-frags (lane n=l16 -> b; k = ks*32 + q*8 + j), strip-invariant
    s8v au[4];
#pragma unroll
    for (int ks = 0; ks < 4; ++ks)
        au[ks] = *(const s8v*)(uT + (size_t)bg * KP + ks * 32 + q * 8);

    f4 acc2[7];
#pragma unroll
    for (int tt = 0; tt < 7; ++tt) acc2[tt] = (f4)0.f;

    for (int s = 0; s < 10; ++s) {
        int vs = v0 + s * 64;
        // ---- dw prefetch: 4 consecutive v per lane (hides under phase-1 MFMA) ----
        s4v dwv[4];
#pragma unroll
        for (int vt = 0; vt < 4; ++vt) {
            int vg = vs + vt * 16 + q * 4;
            dwv[vt] = (vg < V_) ? *(const s4v*)(dwbf + dwrow + vg) : (s4v)0;
        }
        // ---- phase 1: den [64 v x 16 b], D row=v col=b ----
        f4 acc1[4];
#pragma unroll
        for (int vt = 0; vt < 4; ++vt) acc1[vt] = (f4)0.f;
#pragma unroll
        for (int ks = 0; ks < 4; ++ks) {
            int ko = ks * 32 + q * 8;
#pragma unroll
            for (int vt = 0; vt < 4; ++vt) {
                s8v bv = *(const s8v*)(A1 + (size_t)(vs + vt * 16 + l16) * KP + ko);
                acc1[vt] = MFMA(bv, au[ks], acc1[vt]);
            }
        }
        // ---- divide + vv -> LDS [b][v] (one b64 write per vt) ----
        short* buf = vv[s & 1];
#pragma unroll
        for (int vt = 0; vt < 4; ++vt) {
            int vg = vs + vt * 16 + q * 4;
            s4v o;
            if (vg < V_) {
#pragma unroll
                for (int r = 0; r < 4; ++r)
                    o[r] = f2bf(bf2f(dwv[vt][r]) * __builtin_amdgcn_rcpf(acc1[vt][r]));
            } else {
                o = (s4v)0;   // den==0 on pads: avoid 0*inf NaN
            }
            *(s4v*)(buf + (wave * 16 + l16) * LDV + vt * 16 + q * 4) = o;
        }
        __syncthreads();
        // ---- phase 2: C2[t][b] += A2acc[:, strip] @ vv^T (wave owns its 16 b) ----
#pragma unroll
        for (int ks2 = 0; ks2 < 2; ++ks2) {
            int ko = ks2 * 32 + q * 8;
            s8v bb = *(const s8v*)(buf + (wave * 16 + l16) * LDV + ko);
#pragma unroll
            for (int tt = 0; tt < 7; ++tt) {
                s8v a = *(const s8v*)(A2acc + (size_t)(tt * 16 + l16) * VP + vs + ko);
                acc2[tt] = MFMA(a, bb, acc2[tt]);
            }
        }
    }
#pragma unroll
    for (int tt = 0; tt < 7; ++tt)
        *(f4*)(part2 + ((size_t)c * B_ + bg) * TP + tt * 16 + q * 4) = acc2[tt];
}

// reduce partials; mode 0: u = dt/sum -> uf fp32 + uTbf bf16; mode 1: kmvf = sum
__global__ void k_R(const float* __restrict__ part2, const float* __restrict__ dt,
                    float* __restrict__ uf, short* __restrict__ uTbf,
                    float* __restrict__ kmvf, int mode) {
    int id = blockIdx.x * 256 + threadIdx.x;   // < B_*28
    int b = id / 28, t4 = (id % 28) * 4;
    f4 s = (f4)0.f;
    for (int c = 0; c < NC2; ++c)
        s += *(const f4*)(part2 + ((size_t)c * B_ + b) * TP + t4);
    if (mode == 0) {
#pragma unroll
        for (int j = 0; j < 4; ++j) {
            int t = t4 + j;
            float v = (t < T_) ? dt[(size_t)b * T_ + t] / s[j] : 0.f;
            uf[(size_t)b * TP + t] = v;
            uTbf[(size_t)b * KP + t] = f2bf(v);
        }
    } else {
#pragma unroll
        for (int j = 0; j < 4; ++j) kmvf[(size_t)b * TP + t4 + j] = s[j];
    }
}

// rec loss: logits = dt @ (1-M) via MFMA; transpose through LDS; coalesced x reads
__global__ __launch_bounds__(256, 2) void k_rec(const short* __restrict__ dtbf,
                                                const short* __restrict__ W1,
                                                const float* __restrict__ x,
                                                float* __restrict__ recSE,
                                                float* __restrict__ recSXL,
                                                float* __restrict__ recSX) {
    __shared__ float lg[64 * 260];
    int tid = threadIdx.x;
    int wave = tid >> 6, lane = tid & 63, q = lane >> 4, l16 = lane & 15;
    int v0 = blockIdx.x * 256;
    int b0 = blockIdx.y * 64;
    int bw = b0 + wave * 16;
    f4 acc[16];
#pragma unroll
    for (int vt = 0; vt < 16; ++vt) acc[vt] = (f4)0.f;
#pragma unroll
    for (int ks = 0; ks < 4; ++ks) {
        int ko = ks * 32 + q * 8;
        s8v a = *(const s8v*)(dtbf + (size_t)(bw + l16) * KP + ko);
#pragma unroll
        for (int vt = 0; vt < 16; ++vt) {
            s8v bb = *(const s8v*)(W1 + (size_t)(v0 + vt * 16 + l16) * KP + ko);
            acc[vt] = MFMA(a, bb, acc[vt]);
        }
    }
    // D: row=b (q*4+r within wave's 16), col=v (l16) -> LDS [b][v]
#pragma unroll
    for (int vt = 0; vt < 16; ++vt)
#pragma unroll
        for (int r = 0; r < 4; ++r)
            lg[(wave * 16 + q * 4 + r) * 260 + vt * 16 + l16] = acc[vt][r];
    __syncthreads();
    int bl = tid >> 2, seg = tid & 3;
    int bg = b0 + bl;
    float se = 0.f, sxl = 0.f, sx = 0.f;
#pragma unroll
    for (int i = 0; i < 16; ++i) {
        int vl = seg * 64 + i * 4;
        int vg = v0 + vl;
        f4 lo = *(f4*)(&lg[bl * 260 + vl]);
        if (vg + 3 < V_) {
            f4 xv = *(const f4*)(x + (size_t)bg * V_ + vg);
#pragma unroll
            for (int j = 0; j < 4; ++j) {
                se += __expf(lo[j]); sxl += lo[j] * xv[j]; sx += xv[j];
            }
        } else {
#pragma unroll
            for (int j = 0; j < 4; ++j)
                if (vg + j < V_) {
                    float xv = x[(size_t)bg * V_ + vg + j];
                    se += __expf(lo[j]); sxl += lo[j] * xv; sx += xv;
                }
        }
    }
    se  += __shfl_xor(se, 1, 64);  se  += __shfl_xor(se, 2, 64);
    sxl += __shfl_xor(sxl, 1, 64); sxl += __shfl_xor(sxl, 2, 64);
    sx  += __shfl_xor(sx, 1, 64);  sx  += __shfl_xor(sx, 2, 64);
    if (seg == 0) {
        atomicAdd(&recSE[bg], se);
        atomicAdd(&recSXL[bg], sxl);
        atomicAdd(&recSX[bg], sx);
    }
}

__global__ void k_div(const float* __restrict__ uf, const float* __restrict__ kmvf,
                      float* __restrict__ divb) {
    int b = blockIdx.x * 256 + threadIdx.x;
    if (b >= B_) return;
    float s = 0.f;
    for (int t = 0; t < TP; ++t) s += uf[(size_t)b * TP + t] * kmvf[(size_t)b * TP + t];
    divb[b] = s;
}

__global__ void k_final(const float* __restrict__ divb, const float* __restrict__ recSE,
                        const float* __restrict__ recSXL, const float* __restrict__ recSX,
                        const int* __restrict__ wptr, float* __restrict__ out) {
    __shared__ float sA[256], sB[256];
    int tid = threadIdx.x;
    float accS = 0.f, accR = 0.f;
    for (int b = tid; b < B_; b += 256) {
        accS += divb[b];
        accR += recSXL[b] - logf(recSE[b]) * recSX[b];
    }
    sA[tid] = accS; sB[tid] = accR;
    __syncthreads();
    for (int s = 128; s > 0; s >>= 1) {
        if (tid < s) { sA[tid] += sA[tid + s]; sB[tid] += sB[tid + s]; }
        __syncthreads();
    }
    if (tid == 0) {
        float sh = sA[0] / (float)B_;
        float rec = -sB[0] / (float)B_;
        out[0] = rec;
        out[1] = sh;
        out[2] = (float)(*wptr) * rec + sh;
    }
}

extern "C" void kernel_launch(void* const* d_in, const int* in_sizes, int n_in,
                              void* d_out, int out_size, void* d_ws, size_t ws_size,
                              hipStream_t stream) {
    const float* x  = (const float*)d_in[0];
    const float* dt = (const float*)d_in[1];
    const float* dw = (const float*)d_in[2];
    const float* M  = (const float*)d_in[3];
    const int* alpha = (const int*)d_in[5];
    const int* wrec  = (const int*)d_in[6];
    float* out = (float*)d_out;

    char* p = (char*)d_ws;
    short* A1   = (short*)p; p += (size_t)VP * KP * 2;
    short* W1   = (short*)p; p += (size_t)VP * KP * 2;
    short* A2   = (short*)p; p += (size_t)TP * VP * 2;
    short* A2M  = (short*)p; p += (size_t)TP * VP * 2;
    short* uTbf = (short*)p; p += (size_t)B_ * KP * 2;
    short* dtbf = (short*)p; p += (size_t)B_ * KP * 2;
    short* dwbf = (short*)p; p += (size_t)B_ * V_ * 2;
    float* part2 = (float*)p; p += (size_t)NC2 * B_ * TP * 4;
    float* uf    = (float*)p; p += (size_t)B_ * TP * 4;
    float* kmvf  = (float*)p; p += (size_t)B_ * TP * 4;
    float* recSE  = (float*)p; p += B_ * 4;
    float* recSXL = (float*)p; p += B_ * 4;
    float* recSX  = (float*)p; p += B_ * 4;
    float* divb   = (float*)p; p += B_ * 4;

    k_initKT<<<dim3(VP / 32, 4), dim3(32, 8), 0, stream>>>(M, alpha, A1, W1);
    k_initA2<<<(TP * VP) / 256, 256, 0, stream>>>(M, alpha, A2, A2M);
    k_init0<<<(B_ * KP) / 256, 256, 0, stream>>>(uTbf, recSE, recSXL, recSX);
    k_castdw<<<(B_ * V_) / (256 * 8), 256, 0, stream>>>(dw, dwbf);
    k_castdt<<<(B_ * KP) / 256, 256, 0, stream>>>(dt, dtbf);
    k_rec<<<dim3(79, B_ / 64), 256, 0, stream>>>(dtbf, W1, x, recSE, recSXL, recSX);

    for (int it = 0; it < 50; ++it) {
        k_GF<<<dim3((B_ / 64) * NC2), 256, 0, stream>>>(A1, A2, uTbf, dwbf, part2);
        k_R<<<(B_ * 28) / 256, 256, 0, stream>>>(part2, dt, uf, uTbf, kmvf, 0);
    }
    k_GF<<<dim3((B_ / 64) * NC2), 256, 0, stream>>>(A1, A2M, uTbf, dwbf, part2);
    k_R<<<(B_ * 28) / 256, 256, 0, stream>>>(part2, dt, uf, uTbf, kmvf, 1);
    k_div<<<B_ / 256, 256, 0, stream>>>(uf, kmvf, divb);
    k_final<<<1, 256, 0, stream>>>(divb, recSE, recSXL, recSX, wrec, out);
}

// Round 3
// 5110.161 us; speedup vs baseline: 1.6292x; 1.6292x over previous
//
#include <hip/hip_runtime.h>
#include <math.h>

#define B_   2048
#define T_   100
#define V_   20000
#define VP   20480
#define KP   128
#define TP   112
#define NC2  32
#define CH2  640
#define LDV  72    // vv LDS row stride (shorts): 144B = 16B-aligned, 2-way banks (free)

typedef short s8v __attribute__((ext_vector_type(8)));
typedef short s4v __attribute__((ext_vector_type(4)));
typedef float f4  __attribute__((ext_vector_type(4)));

__device__ __forceinline__ short f2bf(float f) {
    unsigned u = __builtin_bit_cast(unsigned, f);
    u += 0x7fffu + ((u >> 16) & 1u);
    return (short)(u >> 16);
}
__device__ __forceinline__ float bf2f(short h) {
    unsigned u = ((unsigned)(unsigned short)h) << 16;
    return __builtin_bit_cast(float, u);
}
#define MFMA(a,b,c) __builtin_amdgcn_mfma_f32_16x16x32_bf16((a),(b),(c),0,0,0)

// A1[v][t] = exp(-lam*M[t][v]) bf16 (t-pad to 128, v-pad to VP, zeros)
// W1[v][t] = 1 - M[t][v] bf16 (same pads)
__global__ void k_initKT(const float* __restrict__ M, const int* __restrict__ alpha,
                         short* __restrict__ A1, short* __restrict__ W1) {
    __shared__ float tile[32][33];
    float lam = (float)(*alpha);
    int v0 = blockIdx.x * 32, t0 = blockIdx.y * 32;
    int tx = threadIdx.x, ty = threadIdx.y;
    for (int j = 0; j < 4; ++j) {
        int t = t0 + ty + 8 * j, v = v0 + tx;
        tile[ty + 8 * j][tx] = (t < T_ && v < V_) ? M[(size_t)t * V_ + v] : 0.f;
    }
    __syncthreads();
    for (int j = 0; j < 4; ++j) {
        int t = t0 + tx, v = v0 + ty + 8 * j;
        float m = tile[tx][ty + 8 * j];
        bool valid = (t < T_) && (v < V_);
        A1[(size_t)v * KP + t] = valid ? f2bf(__expf(-m * lam)) : (short)0;
        W1[(size_t)v * KP + t] = valid ? f2bf(1.f - m) : (short)0;
    }
}

// A2[t][v] = K bf16, A2M[t][v] = K*M bf16; [TP][VP] zero-padded
__global__ void k_initA2(const float* __restrict__ M, const int* __restrict__ alpha,
                         short* __restrict__ A2, short* __restrict__ A2M) {
    float lam = (float)(*alpha);
    size_t id = (size_t)blockIdx.x * 256 + threadIdx.x;   // < TP*VP
    int t = (int)(id / VP), v = (int)(id % VP);
    bool valid = (t < T_) && (v < V_);
    float m = valid ? M[(size_t)t * V_ + v] : 0.f;
    float k = valid ? __expf(-m * lam) : 0.f;
    A2[id]  = valid ? f2bf(k) : (short)0;
    A2M[id] = valid ? f2bf(k * m) : (short)0;
}

// uT init (1/T in bf16, pads zero) + zero rec accumulators
__global__ void k_init0(short* __restrict__ uTbf, float* __restrict__ recSE,
                        float* __restrict__ recSXL, float* __restrict__ recSX) {
    int id = blockIdx.x * 256 + threadIdx.x;   // < B_*KP
    int t = id & (KP - 1);
    uTbf[id] = (t < T_) ? f2bf(0.01f) : (short)0;
    if (id < B_) { recSE[id] = 0.f; recSXL[id] = 0.f; recSX[id] = 0.f; }
}

// dwbf[b][v] = bf16(dw[b][v]) flat
__global__ void k_castdw(const float* __restrict__ dw, short* __restrict__ dwbf) {
    size_t base = ((size_t)blockIdx.x * 256 + threadIdx.x) * 8;   // < B_*V_
    f4 x0 = *(const f4*)(dw + base);
    f4 x1 = *(const f4*)(dw + base + 4);
    s8v o;
    o[0]=f2bf(x0[0]); o[1]=f2bf(x0[1]); o[2]=f2bf(x0[2]); o[3]=f2bf(x0[3]);
    o[4]=f2bf(x1[0]); o[5]=f2bf(x1[1]); o[6]=f2bf(x1[2]); o[7]=f2bf(x1[3]);
    *(s8v*)(dwbf + base) = o;
}

// dtbf[b][t] bf16, t-pad 128
__global__ void k_castdt(const float* __restrict__ dt, short* __restrict__ dtbf) {
    int id = blockIdx.x * 256 + threadIdx.x;   // < B_*KP
    int b = id >> 7, t = id & (KP - 1);
    dtbf[id] = (t < T_) ? f2bf(dt[(size_t)b * T_ + t]) : (short)0;
}

// Fused Sinkhorn iteration kernel — barrier-free, wave-independent:
//   each wave owns 32 b (cb=2) and streams the whole 640-v chunk in 10 strips.
//   per strip: den[v][b] = A1-frag @ uT-frag (MFMA, D row=v col=b)
//              vv = dw/den -> bf16 -> WAVE-PRIVATE LDS [b][v] (no __syncthreads!)
//              C2[t][b] += A2acc[:,strip] @ vv^T (B-frags from own LDS region)
//   No per-strip __syncthreads -> no vmcnt(0) drain; compiler pipelines loads
//   across strips. A raw s_barrier (no drain) keeps the 4 waves loosely aligned
//   so their identical A1/A2 streams hit L1. cb=2 halves operand traffic/MFMA.
//   part2[c][b][t] written once at the end (split-K over 32 chunks).
//   blockIdx swizzled: XCD (id%8) owns chunks 4x..4x+3 (A-slices fit 4MB L2).
__global__ __launch_bounds__(256, 2) void k_GF(const short* __restrict__ A1,
                                               const short* __restrict__ A2acc,
                                               const short* __restrict__ uT,
                                               const short* __restrict__ dwbf,
                                               float* __restrict__ part2) {
    __shared__ short vv[4][32 * LDV];
    int tid = threadIdx.x;
    int wave = tid >> 6, lane = tid & 63, q = lane >> 4, l16 = lane & 15;

    // bijective swizzle: linear id l -> (bx, c) with XCD (l%8) -> chunks 4x..4x+3
    int l = blockIdx.x;
    int j = l & 31, bx = l >> 5;
    int c = ((j & 7) << 2) | (j >> 3);
    int v0 = c * CH2;
    int b0 = bx * 128 + wave * 32;     // wave's 32 b
    short* buf = vv[wave];             // wave-private LDS region

    // hoisted uT B-frags (lane n=l16 -> b; k = ks*32 + q*8 + j), strip-invariant
    s8v au[2][4];
#pragma unroll
    for (int cb = 0; cb < 2; ++cb)
#pragma unroll
        for (int ks = 0; ks < 4; ++ks)
            au[cb][ks] = *(const s8v*)(uT + (size_t)(b0 + cb * 16 + l16) * KP + ks * 32 + q * 8);

    f4 acc2[7][2];
#pragma unroll
    for (int tt = 0; tt < 7; ++tt) { acc2[tt][0] = (f4)0.f; acc2[tt][1] = (f4)0.f; }

    for (int s = 0; s < 10; ++s) {
        int vs = v0 + s * 64;
        // ---- dw prefetch: 4 consecutive v per lane, per cb-half ----
        s4v dwv[2][4];
#pragma unroll
        for (int cb = 0; cb < 2; ++cb)
#pragma unroll
            for (int vt = 0; vt < 4; ++vt) {
                int vg = vs + vt * 16 + q * 4;
                dwv[cb][vt] = (vg < V_)
                    ? *(const s4v*)(dwbf + (size_t)(b0 + cb * 16 + l16) * V_ + vg)
                    : (s4v)0;
            }
        // ---- phase 1: den [64 v x 32 b], D row=v col=b; A-loads feed 2 cb ----
        f4 acc1[2][4];
#pragma unroll
        for (int cb = 0; cb < 2; ++cb)
#pragma unroll
            for (int vt = 0; vt < 4; ++vt) acc1[cb][vt] = (f4)0.f;
#pragma unroll
        for (int ks = 0; ks < 4; ++ks) {
            int ko = ks * 32 + q * 8;
            s8v bv[4];
#pragma unroll
            for (int vt = 0; vt < 4; ++vt)
                bv[vt] = *(const s8v*)(A1 + (size_t)(vs + vt * 16 + l16) * KP + ko);
#pragma unroll
            for (int cb = 0; cb < 2; ++cb)
#pragma unroll
                for (int vt = 0; vt < 4; ++vt)
                    acc1[cb][vt] = MFMA(bv[vt], au[cb][ks], acc1[cb][vt]);
        }
        // ---- divide + vv -> wave-private LDS [b][v] (one b64 write per cb,vt) ----
#pragma unroll
        for (int cb = 0; cb < 2; ++cb)
#pragma unroll
            for (int vt = 0; vt < 4; ++vt) {
                int vg = vs + vt * 16 + q * 4;
                s4v o;
                if (vg < V_) {
#pragma unroll
                    for (int r = 0; r < 4; ++r)
                        o[r] = f2bf(bf2f(dwv[cb][vt][r]) * __builtin_amdgcn_rcpf(acc1[cb][vt][r]));
                } else {
                    o = (s4v)0;   // den==0 on pads: avoid 0*inf NaN
                }
                *(s4v*)(buf + (cb * 16 + l16) * LDV + vt * 16 + q * 4) = o;
            }
        // intra-wave LDS RAW: wait writes, pin ordering (rule #18)
        asm volatile("s_waitcnt lgkmcnt(0)" ::: "memory");
        __builtin_amdgcn_sched_barrier(0);
        // ---- phase 2: C2[t][b] += A2acc[:, strip] @ vv^T (own LDS, no barrier) ----
#pragma unroll
        for (int ks2 = 0; ks2 < 2; ++ks2) {
            int ko = ks2 * 32 + q * 8;
            s8v bb[2];
#pragma unroll
            for (int cb = 0; cb < 2; ++cb)
                bb[cb] = *(const s8v*)(buf + (cb * 16 + l16) * LDV + ko);
#pragma unroll
            for (int tt = 0; tt < 7; ++tt) {
                s8v a = *(const s8v*)(A2acc + (size_t)(tt * 16 + l16) * VP + vs + ko);
#pragma unroll
                for (int cb = 0; cb < 2; ++cb)
                    acc2[tt][cb] = MFMA(a, bb[cb], acc2[tt][cb]);
            }
        }
        // loose phase-alignment only (raw barrier: no vmcnt/lgkmcnt drain) so the
        // 4 waves' identical A1/A2 streams share L1; not needed for correctness.
        __builtin_amdgcn_s_barrier();
    }
#pragma unroll
    for (int tt = 0; tt < 7; ++tt)
#pragma unroll
        for (int cb = 0; cb < 2; ++cb) {
            int bg = b0 + cb * 16 + l16;
            *(f4*)(part2 + ((size_t)c * B_ + bg) * TP + tt * 16 + q * 4) = acc2[tt][cb];
        }
}

// reduce partials; mode 0: u = dt/sum -> uf fp32 + uTbf bf16; mode 1: kmvf = sum
__global__ void k_R(const float* __restrict__ part2, const float* __restrict__ dt,
                    float* __restrict__ uf, short* __restrict__ uTbf,
                    float* __restrict__ kmvf, int mode) {
    int id = blockIdx.x * 256 + threadIdx.x;   // < B_*28
    int b = id / 28, t4 = (id % 28) * 4;
    f4 s = (f4)0.f;
    for (int c = 0; c < NC2; ++c)
        s += *(const f4*)(part2 + ((size_t)c * B_ + b) * TP + t4);
    if (mode == 0) {
#pragma unroll
        for (int j = 0; j < 4; ++j) {
            int t = t4 + j;
            float v = (t < T_) ? dt[(size_t)b * T_ + t] / s[j] : 0.f;
            uf[(size_t)b * TP + t] = v;
            uTbf[(size_t)b * KP + t] = f2bf(v);
        }
    } else {
#pragma unroll
        for (int j = 0; j < 4; ++j) kmvf[(size_t)b * TP + t4 + j] = s[j];
    }
}

// rec loss: logits = dt @ (1-M) via MFMA; transpose through LDS; coalesced x reads
__global__ __launch_bounds__(256, 2) void k_rec(const short* __restrict__ dtbf,
                                                const short* __restrict__ W1,
                                                const float* __restrict__ x,
                                                float* __restrict__ recSE,
                                                float* __restrict__ recSXL,
                                                float* __restrict__ recSX) {
    __shared__ float lg[64 * 260];
    int tid = threadIdx.x;
    int wave = tid >> 6, lane = tid & 63, q = lane >> 4, l16 = lane & 15;
    int v0 = blockIdx.x * 256;
    int b0 = blockIdx.y * 64;
    int bw = b0 + wave * 16;
    f4 acc[16];
#pragma unroll
    for (int vt = 0; vt < 16; ++vt) acc[vt] = (f4)0.f;
#pragma unroll
    for (int ks = 0; ks < 4; ++ks) {
        int ko = ks * 32 + q * 8;
        s8v a = *(const s8v*)(dtbf + (size_t)(bw + l16) * KP + ko);
#pragma unroll
        for (int vt = 0; vt < 16; ++vt) {
            s8v bb = *(const s8v*)(W1 + (size_t)(v0 + vt * 16 + l16) * KP + ko);
            acc[vt] = MFMA(a, bb, acc[vt]);
        }
    }
    // D: row=b (q*4+r within wave's 16), col=v (l16) -> LDS [b][v]
#pragma unroll
    for (int vt = 0; vt < 16; ++vt)
#pragma unroll
        for (int r = 0; r < 4; ++r)
            lg[(wave * 16 + q * 4 + r) * 260 + vt * 16 + l16] = acc[vt][r];
    __syncthreads();
    int bl = tid >> 2, seg = tid & 3;
    int bg = b0 + bl;
    float se = 0.f, sxl = 0.f, sx = 0.f;
#pragma unroll
    for (int i = 0; i < 16; ++i) {
        int vl = seg * 64 + i * 4;
        int vg = v0 + vl;
        f4 lo = *(f4*)(&lg[bl * 260 + vl]);
        if (vg + 3 < V_) {
            f4 xv = *(const f4*)(x + (size_t)bg * V_ + vg);
#pragma unroll
            for (int j = 0; j < 4; ++j) {
                se += __expf(lo[j]); sxl += lo[j] * xv[j]; sx += xv[j];
            }
        } else {
#pragma unroll
            for (int j = 0; j < 4; ++j)
                if (vg + j < V_) {
                    float xv = x[(size_t)bg * V_ + vg + j];
                    se += __expf(lo[j]); sxl += lo[j] * xv; sx += xv;
                }
        }
    }
    se  += __shfl_xor(se, 1, 64);  se  += __shfl_xor(se, 2, 64);
    sxl += __shfl_xor(sxl, 1, 64); sxl += __shfl_xor(sxl, 2, 64);
    sx  += __shfl_xor(sx, 1, 64);  sx  += __shfl_xor(sx, 2, 64);
    if (seg == 0) {
        atomicAdd(&recSE[bg], se);
        atomicAdd(&recSXL[bg], sxl);
        atomicAdd(&recSX[bg], sx);
    }
}

__global__ void k_div(const float* __restrict__ uf, const float* __restrict__ kmvf,
                      float* __restrict__ divb) {
    int b = blockIdx.x * 256 + threadIdx.x;
    if (b >= B_) return;
    float s = 0.f;
    for (int t = 0; t < TP; ++t) s += uf[(size_t)b * TP + t] * kmvf[(size_t)b * TP + t];
    divb[b] = s;
}

__global__ void k_final(const float* __restrict__ divb, const float* __restrict__ recSE,
                        const float* __restrict__ recSXL, const float* __restrict__ recSX,
                        const int* __restrict__ wptr, float* __restrict__ out) {
    __shared__ float sA[256], sB[256];
    int tid = threadIdx.x;
    float accS = 0.f, accR = 0.f;
    for (int b = tid; b < B_; b += 256) {
        accS += divb[b];
        accR += recSXL[b] - logf(recSE[b]) * recSX[b];
    }
    sA[tid] = accS; sB[tid] = accR;
    __syncthreads();
    for (int s = 128; s > 0; s >>= 1) {
        if (tid < s) { sA[tid] += sA[tid + s]; sB[tid] += sB[tid + s]; }
        __syncthreads();
    }
    if (tid == 0) {
        float sh = sA[0] / (float)B_;
        float rec = -sB[0] / (float)B_;
        out[0] = rec;
        out[1] = sh;
        out[2] = (float)(*wptr) * rec + sh;
    }
}

extern "C" void kernel_launch(void* const* d_in, const int* in_sizes, int n_in,
                              void* d_out, int out_size, void* d_ws, size_t ws_size,
                              hipStream_t stream) {
    const float* x  = (const float*)d_in[0];
    const float* dt = (const float*)d_in[1];
    const float* dw = (const float*)d_in[2];
    const float* M  = (const float*)d_in[3];
    const int* alpha = (const int*)d_in[5];
    const int* wrec  = (const int*)d_in[6];
    float* out = (float*)d_out;

    char* p = (char*)d_ws;
    short* A1   = (short*)p; p += (size_t)VP * KP * 2;
    short* W1   = (short*)p; p += (size_t)VP * KP * 2;
    short* A2   = (short*)p; p += (size_t)TP * VP * 2;
    short* A2M  = (short*)p; p += (size_t)TP * VP * 2;
    short* uTbf = (short*)p; p += (size_t)B_ * KP * 2;
    short* dtbf = (short*)p; p += (size_t)B_ * KP * 2;
    short* dwbf = (short*)p; p += (size_t)B_ * V_ * 2;
    float* part2 = (float*)p; p += (size_t)NC2 * B_ * TP * 4;
    float* uf    = (float*)p; p += (size_t)B_ * TP * 4;
    float* kmvf  = (float*)p; p += (size_t)B_ * TP * 4;
    float* recSE  = (float*)p; p += B_ * 4;
    float* recSXL = (float*)p; p += B_ * 4;
    float* recSX  = (float*)p; p += B_ * 4;
    float* divb   = (float*)p; p += B_ * 4;

    k_initKT<<<dim3(VP / 32, 4), dim3(32, 8), 0, stream>>>(M, alpha, A1, W1);
    k_initA2<<<(TP * VP) / 256, 256, 0, stream>>>(M, alpha, A2, A2M);
    k_init0<<<(B_ * KP) / 256, 256, 0, stream>>>(uTbf, recSE, recSXL, recSX);
    k_castdw<<<(B_ * V_) / (256 * 8), 256, 0, stream>>>(dw, dwbf);
    k_castdt<<<(B_ * KP) / 256, 256, 0, stream>>>(dt, dtbf);
    k_rec<<<dim3(79, B_ / 64), 256, 0, stream>>>(dtbf, W1, x, recSE, recSXL, recSX);

    for (int it = 0; it < 50; ++it) {
        k_GF<<<dim3((B_ / 128) * NC2), 256, 0, stream>>>(A1, A2, uTbf, dwbf, part2);
        k_R<<<(B_ * 28) / 256, 256, 0, stream>>>(part2, dt, uf, uTbf, kmvf, 0);
    }
    k_GF<<<dim3((B_ / 128) * NC2), 256, 0, stream>>>(A1, A2M, uTbf, dwbf, part2);
    k_R<<<(B_ * 28) / 256, 256, 0, stream>>>(part2, dt, uf, uTbf, kmvf, 1);
    k_div<<<B_ / 256, 256, 0, stream>>>(uf, kmvf, divb);
    k_final<<<1, 256, 0, stream>>>(divb, recSE, recSXL, recSX, wrec, out);
}

// Round 4
// 4991.734 us; speedup vs baseline: 1.6679x; 1.0237x over previous
//
#include <hip/hip_runtime.h>
#include <math.h>

#define B_   2048
#define T_   100
#define V_   20000
#define VP   20480
#define KP   128
#define TP   112
#define NC2  32
#define CH2  640
#define LDV  72    // vv LDS row stride (shorts): 144B = 16B-aligned, 2-way banks (free)

typedef short s8v __attribute__((ext_vector_type(8)));
typedef short s4v __attribute__((ext_vector_type(4)));
typedef float f4  __attribute__((ext_vector_type(4)));

__device__ __forceinline__ short f2bf(float f) {
    unsigned u = __builtin_bit_cast(unsigned, f);
    u += 0x7fffu + ((u >> 16) & 1u);
    return (short)(u >> 16);
}
__device__ __forceinline__ float bf2f(short h) {
    unsigned u = ((unsigned)(unsigned short)h) << 16;
    return __builtin_bit_cast(float, u);
}
#define MFMA(a,b,c) __builtin_amdgcn_mfma_f32_16x16x32_bf16((a),(b),(c),0,0,0)

// A1[v][t] = exp(-lam*M[t][v]) bf16 (t-pad to 128, v-pad to VP, zeros)
// W1[v][t] = 1 - M[t][v] bf16 (same pads)
__global__ void k_initKT(const float* __restrict__ M, const int* __restrict__ alpha,
                         short* __restrict__ A1, short* __restrict__ W1) {
    __shared__ float tile[32][33];
    float lam = (float)(*alpha);
    int v0 = blockIdx.x * 32, t0 = blockIdx.y * 32;
    int tx = threadIdx.x, ty = threadIdx.y;
    for (int j = 0; j < 4; ++j) {
        int t = t0 + ty + 8 * j, v = v0 + tx;
        tile[ty + 8 * j][tx] = (t < T_ && v < V_) ? M[(size_t)t * V_ + v] : 0.f;
    }
    __syncthreads();
    for (int j = 0; j < 4; ++j) {
        int t = t0 + tx, v = v0 + ty + 8 * j;
        float m = tile[tx][ty + 8 * j];
        bool valid = (t < T_) && (v < V_);
        A1[(size_t)v * KP + t] = valid ? f2bf(__expf(-m * lam)) : (short)0;
        W1[(size_t)v * KP + t] = valid ? f2bf(1.f - m) : (short)0;
    }
}

// A2[t][v] = K bf16, A2M[t][v] = K*M bf16; [TP][VP] zero-padded
__global__ void k_initA2(const float* __restrict__ M, const int* __restrict__ alpha,
                         short* __restrict__ A2, short* __restrict__ A2M) {
    float lam = (float)(*alpha);
    size_t id = (size_t)blockIdx.x * 256 + threadIdx.x;   // < TP*VP
    int t = (int)(id / VP), v = (int)(id % VP);
    bool valid = (t < T_) && (v < V_);
    float m = valid ? M[(size_t)t * V_ + v] : 0.f;
    float k = valid ? __expf(-m * lam) : 0.f;
    A2[id]  = valid ? f2bf(k) : (short)0;
    A2M[id] = valid ? f2bf(k * m) : (short)0;
}

// uT init (1/T in bf16, pads zero) + zero rec accumulators
__global__ void k_init0(short* __restrict__ uTbf, float* __restrict__ recSE,
                        float* __restrict__ recSXL, float* __restrict__ recSX) {
    int id = blockIdx.x * 256 + threadIdx.x;   // < B_*KP
    int t = id & (KP - 1);
    uTbf[id] = (t < T_) ? f2bf(0.01f) : (short)0;
    if (id < B_) { recSE[id] = 0.f; recSXL[id] = 0.f; recSX[id] = 0.f; }
}

// dwbf[b][v] = bf16(dw[b][v]) flat
__global__ void k_castdw(const float* __restrict__ dw, short* __restrict__ dwbf) {
    size_t base = ((size_t)blockIdx.x * 256 + threadIdx.x) * 8;   // < B_*V_
    f4 x0 = *(const f4*)(dw + base);
    f4 x1 = *(const f4*)(dw + base + 4);
    s8v o;
    o[0]=f2bf(x0[0]); o[1]=f2bf(x0[1]); o[2]=f2bf(x0[2]); o[3]=f2bf(x0[3]);
    o[4]=f2bf(x1[0]); o[5]=f2bf(x1[1]); o[6]=f2bf(x1[2]); o[7]=f2bf(x1[3]);
    *(s8v*)(dwbf + base) = o;
}

// dtbf[b][t] bf16, t-pad 128
__global__ void k_castdt(const float* __restrict__ dt, short* __restrict__ dtbf) {
    int id = blockIdx.x * 256 + threadIdx.x;   // < B_*KP
    int b = id >> 7, t = id & (KP - 1);
    dtbf[id] = (t < T_) ? f2bf(dt[(size_t)b * T_ + t]) : (short)0;
}

// Fused Sinkhorn iteration kernel — barrier-free, wave-independent:
//   each wave owns 32 b (cb=2) and streams the whole 640-v chunk in 10 strips.
//   per strip: dw + A2 frags prefetched at top (latency hides under phase 1)
//              den[v][b] = A1-frag @ uT-frag (MFMA, D row=v col=b)
//              vv = dw/den -> bf16 -> WAVE-PRIVATE LDS [b][v] (no __syncthreads)
//              C2[t][b] += a2r @ vv^T (B-frags from own LDS region; compiler
//              inserts the precise lgkmcnt for the ds_write->ds_read RAW)
//   Raw s_barrier per strip keeps the 4 waves loosely aligned for L1 sharing
//   (no vmcnt/lgkmcnt drain; not needed for correctness).
//   part2[c][b][t] written once at the end (split-K over 32 chunks).
//   blockIdx swizzled: XCD (id%8) owns chunks 4x..4x+3 (A-slices fit 4MB L2).
__global__ __launch_bounds__(256, 2) void k_GF(const short* __restrict__ A1,
                                               const short* __restrict__ A2acc,
                                               const short* __restrict__ uT,
                                               const short* __restrict__ dwbf,
                                               float* __restrict__ part2) {
    __shared__ short vv[4][32 * LDV];
    int tid = threadIdx.x;
    int wave = tid >> 6, lane = tid & 63, q = lane >> 4, l16 = lane & 15;

    // bijective swizzle: linear id l -> (bx, c) with XCD (l%8) -> chunks 4x..4x+3
    int l = blockIdx.x;
    int j = l & 31, bx = l >> 5;
    int c = ((j & 7) << 2) | (j >> 3);
    int v0 = c * CH2;
    int b0 = bx * 128 + wave * 32;     // wave's 32 b
    short* buf = vv[wave];             // wave-private LDS region

    // hoisted uT B-frags (lane n=l16 -> b; k = ks*32 + q*8 + j), strip-invariant
    s8v au[2][4];
#pragma unroll
    for (int cb = 0; cb < 2; ++cb)
#pragma unroll
        for (int ks = 0; ks < 4; ++ks)
            au[cb][ks] = *(const s8v*)(uT + (size_t)(b0 + cb * 16 + l16) * KP + ks * 32 + q * 8);

    f4 acc2[7][2];
#pragma unroll
    for (int tt = 0; tt < 7; ++tt) { acc2[tt][0] = (f4)0.f; acc2[tt][1] = (f4)0.f; }

    for (int s = 0; s < 10; ++s) {
        int vs = v0 + s * 64;
        // ---- dw prefetch: 4 consecutive v per lane, per cb-half ----
        s4v dwv[2][4];
#pragma unroll
        for (int cb = 0; cb < 2; ++cb)
#pragma unroll
            for (int vt = 0; vt < 4; ++vt) {
                int vg = vs + vt * 16 + q * 4;
                dwv[cb][vt] = (vg < V_)
                    ? *(const s4v*)(dwbf + (size_t)(b0 + cb * 16 + l16) * V_ + vg)
                    : (s4v)0;
            }
        // ---- A2 frag prefetch (latency hides under phase 1 + divide) ----
        s8v a2r[2][7];
#pragma unroll
        for (int ks2 = 0; ks2 < 2; ++ks2)
#pragma unroll
            for (int tt = 0; tt < 7; ++tt)
                a2r[ks2][tt] = *(const s8v*)(A2acc + (size_t)(tt * 16 + l16) * VP
                                             + vs + ks2 * 32 + q * 8);
        // ---- phase 1: den [64 v x 32 b], D row=v col=b; A-loads feed 2 cb ----
        f4 acc1[2][4];
#pragma unroll
        for (int cb = 0; cb < 2; ++cb)
#pragma unroll
            for (int vt = 0; vt < 4; ++vt) acc1[cb][vt] = (f4)0.f;
#pragma unroll
        for (int ks = 0; ks < 4; ++ks) {
            int ko = ks * 32 + q * 8;
            s8v bv[4];
#pragma unroll
            for (int vt = 0; vt < 4; ++vt)
                bv[vt] = *(const s8v*)(A1 + (size_t)(vs + vt * 16 + l16) * KP + ko);
#pragma unroll
            for (int cb = 0; cb < 2; ++cb)
#pragma unroll
                for (int vt = 0; vt < 4; ++vt)
                    acc1[cb][vt] = MFMA(bv[vt], au[cb][ks], acc1[cb][vt]);
        }
        // ---- divide + vv -> wave-private LDS [b][v] (one b64 write per cb,vt) ----
#pragma unroll
        for (int cb = 0; cb < 2; ++cb)
#pragma unroll
            for (int vt = 0; vt < 4; ++vt) {
                int vg = vs + vt * 16 + q * 4;
                s4v o;
                if (vg < V_) {
#pragma unroll
                    for (int r = 0; r < 4; ++r)
                        o[r] = f2bf(bf2f(dwv[cb][vt][r]) * __builtin_amdgcn_rcpf(acc1[cb][vt][r]));
                } else {
                    o = (s4v)0;   // den==0 on pads: avoid 0*inf NaN
                }
                *(s4v*)(buf + (cb * 16 + l16) * LDV + vt * 16 + q * 4) = o;
            }
        // ---- phase 2: C2[t][b] += a2r @ vv^T (own LDS; compiler orders RAW) ----
#pragma unroll
        for (int ks2 = 0; ks2 < 2; ++ks2) {
            int ko = ks2 * 32 + q * 8;
            s8v bb[2];
#pragma unroll
            for (int cb = 0; cb < 2; ++cb)
                bb[cb] = *(const s8v*)(buf + (cb * 16 + l16) * LDV + ko);
#pragma unroll
            for (int tt = 0; tt < 7; ++tt)
#pragma unroll
                for (int cb = 0; cb < 2; ++cb)
                    acc2[tt][cb] = MFMA(a2r[ks2][tt], bb[cb], acc2[tt][cb]);
        }
        // loose phase-alignment only (raw barrier: no vmcnt/lgkmcnt drain) so the
        // 4 waves' identical A1/A2 streams share L1; not needed for correctness.
        __builtin_amdgcn_s_barrier();
    }
#pragma unroll
    for (int tt = 0; tt < 7; ++tt)
#pragma unroll
        for (int cb = 0; cb < 2; ++cb) {
            int bg = b0 + cb * 16 + l16;
            *(f4*)(part2 + ((size_t)c * B_ + bg) * TP + tt * 16 + q * 4) = acc2[tt][cb];
        }
}

// reduce partials; mode 0: u = dt/sum -> uf fp32 + uTbf bf16; mode 1: kmvf = sum
__global__ void k_R(const float* __restrict__ part2, const float* __restrict__ dt,
                    float* __restrict__ uf, short* __restrict__ uTbf,
                    float* __restrict__ kmvf, int mode) {
    int id = blockIdx.x * 256 + threadIdx.x;   // < B_*28
    int b = id / 28, t4 = (id % 28) * 4;
    f4 s = (f4)0.f;
    for (int c = 0; c < NC2; ++c)
        s += *(const f4*)(part2 + ((size_t)c * B_ + b) * TP + t4);
    if (mode == 0) {
#pragma unroll
        for (int j = 0; j < 4; ++j) {
            int t = t4 + j;
            float v = (t < T_) ? dt[(size_t)b * T_ + t] / s[j] : 0.f;
            uf[(size_t)b * TP + t] = v;
            uTbf[(size_t)b * KP + t] = f2bf(v);
        }
    } else {
#pragma unroll
        for (int j = 0; j < 4; ++j) kmvf[(size_t)b * TP + t4 + j] = s[j];
    }
}

// rec loss: logits = (1-M)^T-frag @ dt-frag via MFMA (D row=v col=b):
//   each lane holds 4 consecutive v at fixed b -> x read is one f4 per tile.
//   No LDS, no __syncthreads, no bank conflicts; reduce over v via shfl_xor(16/32).
__global__ __launch_bounds__(256, 4) void k_rec(const short* __restrict__ dtbf,
                                                const short* __restrict__ W1,
                                                const float* __restrict__ x,
                                                float* __restrict__ recSE,
                                                float* __restrict__ recSXL,
                                                float* __restrict__ recSX) {
    int tid = threadIdx.x;
    int wave = tid >> 6, lane = tid & 63, q = lane >> 4, l16 = lane & 15;
    int v0 = blockIdx.x * 256;
    int b0 = blockIdx.y * 64;
    int bg = b0 + wave * 16 + l16;     // this thread's b
    // B-frags: dt row bg (lane n=l16 -> b)
    s8v a[4];
#pragma unroll
    for (int ks = 0; ks < 4; ++ks)
        a[ks] = *(const s8v*)(dtbf + (size_t)bg * KP + ks * 32 + q * 8);
    f4 acc[16];
#pragma unroll
    for (int vt = 0; vt < 16; ++vt) acc[vt] = (f4)0.f;
#pragma unroll
    for (int ks = 0; ks < 4; ++ks) {
        int ko = ks * 32 + q * 8;
#pragma unroll
        for (int vt = 0; vt < 16; ++vt) {
            s8v w = *(const s8v*)(W1 + (size_t)(v0 + vt * 16 + l16) * KP + ko);
            acc[vt] = MFMA(w, a[ks], acc[vt]);
        }
    }
    // D: row=v (vt*16 + q*4 + r), col=b (l16) -> per lane 4 consecutive v at bg
    float se = 0.f, sxl = 0.f, sx = 0.f;
#pragma unroll
    for (int vt = 0; vt < 16; ++vt) {
        int vg = v0 + vt * 16 + q * 4;
        if (vg < V_) {   // vg,V_ both %4==0 -> full f4 in-bounds
            f4 xv = *(const f4*)(x + (size_t)bg * V_ + vg);
#pragma unroll
            for (int r = 0; r < 4; ++r) {
                float lo = acc[vt][r];
                se += __expf(lo); sxl += lo * xv[r]; sx += xv[r];
            }
        }
    }
    // reduce over q (lanes ^16, ^32) -> q==0 lanes hold totals for bg
    se  += __shfl_xor(se, 16, 64);  se  += __shfl_xor(se, 32, 64);
    sxl += __shfl_xor(sxl, 16, 64); sxl += __shfl_xor(sxl, 32, 64);
    sx  += __shfl_xor(sx, 16, 64);  sx  += __shfl_xor(sx, 32, 64);
    if (q == 0) {
        atomicAdd(&recSE[bg], se);
        atomicAdd(&recSXL[bg], sxl);
        atomicAdd(&recSX[bg], sx);
    }
}

__global__ void k_div(const float* __restrict__ uf, const float* __restrict__ kmvf,
                      float* __restrict__ divb) {
    int b = blockIdx.x * 256 + threadIdx.x;
    if (b >= B_) return;
    float s = 0.f;
    for (int t = 0; t < TP; ++t) s += uf[(size_t)b * TP + t] * kmvf[(size_t)b * TP + t];
    divb[b] = s;
}

__global__ void k_final(const float* __restrict__ divb, const float* __restrict__ recSE,
                        const float* __restrict__ recSXL, const float* __restrict__ recSX,
                        const int* __restrict__ wptr, float* __restrict__ out) {
    __shared__ float sA[256], sB[256];
    int tid = threadIdx.x;
    float accS = 0.f, accR = 0.f;
    for (int b = tid; b < B_; b += 256) {
        accS += divb[b];
        accR += recSXL[b] - logf(recSE[b]) * recSX[b];
    }
    sA[tid] = accS; sB[tid] = accR;
    __syncthreads();
    for (int s = 128; s > 0; s >>= 1) {
        if (tid < s) { sA[tid] += sA[tid + s]; sB[tid] += sB[tid + s]; }
        __syncthreads();
    }
    if (tid == 0) {
        float sh = sA[0] / (float)B_;
        float rec = -sB[0] / (float)B_;
        out[0] = rec;
        out[1] = sh;
        out[2] = (float)(*wptr) * rec + sh;
    }
}

extern "C" void kernel_launch(void* const* d_in, const int* in_sizes, int n_in,
                              void* d_out, int out_size, void* d_ws, size_t ws_size,
                              hipStream_t stream) {
    const float* x  = (const float*)d_in[0];
    const float* dt = (const float*)d_in[1];
    const float* dw = (const float*)d_in[2];
    const float* M  = (const float*)d_in[3];
    const int* alpha = (const int*)d_in[5];
    const int* wrec  = (const int*)d_in[6];
    float* out = (float*)d_out;

    char* p = (char*)d_ws;
    short* A1   = (short*)p; p += (size_t)VP * KP * 2;
    short* W1   = (short*)p; p += (size_t)VP * KP * 2;
    short* A2   = (short*)p; p += (size_t)TP * VP * 2;
    short* A2M  = (short*)p; p += (size_t)TP * VP * 2;
    short* uTbf = (short*)p; p += (size_t)B_ * KP * 2;
    short* dtbf = (short*)p; p += (size_t)B_ * KP * 2;
    short* dwbf = (short*)p; p += (size_t)B_ * V_ * 2;
    float* part2 = (float*)p; p += (size_t)NC2 * B_ * TP * 4;
    float* uf    = (float*)p; p += (size_t)B_ * TP * 4;
    float* kmvf  = (float*)p; p += (size_t)B_ * TP * 4;
    float* recSE  = (float*)p; p += B_ * 4;
    float* recSXL = (float*)p; p += B_ * 4;
    float* recSX  = (float*)p; p += B_ * 4;
    float* divb   = (float*)p; p += B_ * 4;

    k_initKT<<<dim3(VP / 32, 4), dim3(32, 8), 0, stream>>>(M, alpha, A1, W1);
    k_initA2<<<(TP * VP) / 256, 256, 0, stream>>>(M, alpha, A2, A2M);
    k_init0<<<(B_ * KP) / 256, 256, 0, stream>>>(uTbf, recSE, recSXL, recSX);
    k_castdw<<<(B_ * V_) / (256 * 8), 256, 0, stream>>>(dw, dwbf);
    k_castdt<<<(B_ * KP) / 256, 256, 0, stream>>>(dt, dtbf);
    k_rec<<<dim3(79, B_ / 64), 256, 0, stream>>>(dtbf, W1, x, recSE, recSXL, recSX);

    for (int it = 0; it < 50; ++it) {
        k_GF<<<dim3((B_ / 128) * NC2), 256, 0, stream>>>(A1, A2, uTbf, dwbf, part2);
        k_R<<<(B_ * 28) / 256, 256, 0, stream>>>(part2, dt, uf, uTbf, kmvf, 0);
    }
    k_GF<<<dim3((B_ / 128) * NC2), 256, 0, stream>>>(A1, A2M, uTbf, dwbf, part2);
    k_R<<<(B_ * 28) / 256, 256, 0, stream>>>(part2, dt, uf, uTbf, kmvf, 1);
    k_div<<<B_ / 256, 256, 0, stream>>>(uf, kmvf, divb);
    k_final<<<1, 256, 0, stream>>>(divb, recSE, recSXL, recSX, wrec, out);
}